// Round 3
// baseline (565.481 us; speedup 1.0000x reference)
//
#include <hip/hip_runtime.h>
#include <stdint.h>

typedef __bf16 bf16;
typedef __bf16 bf16x8 __attribute__((ext_vector_type(8)));
typedef float f32x4 __attribute__((ext_vector_type(4)));

#define B_DIM 4096
#define HID   1024
#define KPSZ  256

#define BM  128   // fallback m-tile
#define BNH 32    // fallback n-tile within H
#define BK  64    // fallback k-step

// new-path tile geometry
#define BM2 256   // m-tile (batch rows)
#define BN2 64    // h-cols per block (x4 gates = 256 weight rows staged)
#define BK2 32    // k-step

// ---- runtime dtype detection (unchanged from passing round) --------------
__device__ __forceinline__ bool detect_b16(const void* kps) {
  const uint16_t* k16 = (const uint16_t*)kps;
  int lane = threadIdx.x & 63;
  int c = 0;
#pragma unroll
  for (int j = 0; j < 8; ++j) {
    uint16_t v = k16[(lane * 8 + j) * 2];
    int e = (v >> 7) & 0xFF;
    c += (e >= 100 && e <= 140) ? 1 : 0;
  }
#pragma unroll
  for (int s = 1; s < 64; s <<= 1) c += __shfl_xor(c, s, 64);
  return c > 256;
}

__device__ __forceinline__ bf16x8 load8(const void* base, size_t off, bool b16) {
  if (b16) {
    return *(const bf16x8*)((const bf16*)base + off);
  } else {
    const float* f = (const float*)base + off;
    float4 lo = *(const float4*)f;
    float4 hi = *(const float4*)(f + 4);
    bf16x8 r;
    r[0] = (bf16)lo.x; r[1] = (bf16)lo.y; r[2] = (bf16)lo.z; r[3] = (bf16)lo.w;
    r[4] = (bf16)hi.x; r[5] = (bf16)hi.y; r[6] = (bf16)hi.z; r[7] = (bf16)hi.w;
    return r;
  }
}
__device__ __forceinline__ float ldg1(const void* p, size_t i, bool b16) {
  return b16 ? (float)((const bf16*)p)[i] : ((const float*)p)[i];
}
__device__ __forceinline__ void stg1(void* p, size_t i, float v, bool b16) {
  if (b16) ((bf16*)p)[i] = (bf16)v;
  else     ((float*)p)[i] = v;
}

__device__ __forceinline__ float sigm(float x) {
  return 1.0f / (1.0f + __expf(-x));
}
__device__ __forceinline__ float tanhx(float x) {
  float e = __expf(-2.0f * fabsf(x));
  float t = (1.0f - e) / (1.0f + e);
  return x < 0.0f ? -t : t;
}

// XOR-swizzled LDS index (used by fallback + emb part of prep kernel)
__device__ __forceinline__ int sw(int row, int col8) {
  return row * BK + (col8 ^ ((row & 7) << 3));
}

// async global->LDS, 16B per lane; dest base must be wave-uniform
__device__ __forceinline__ void gl16(const bf16* g, bf16* l) {
  __builtin_amdgcn_global_load_lds(
      (const __attribute__((address_space(1))) void*)g,
      (__attribute__((address_space(3))) void*)l, 16, 0, 0);
}

// ======================= OLD PATH (fallback, verified) =====================

__global__ __launch_bounds__(256)
void emb_kernel(const void* __restrict__ kps, const void* __restrict__ W,
                const void* __restrict__ bias, void* __restrict__ out) {
  __shared__ __align__(16) bf16 sA[BM * BK];   // 16 KB
  __shared__ __align__(16) bf16 sB[BNH * BK];  // 4 KB

  const bool b16 = detect_b16(kps);
  const int n0   = blockIdx.x * BNH;
  const int m0   = blockIdx.y * BM;
  const int tid  = threadIdx.x;
  const int wave = tid >> 6;
  const int lane = tid & 63;
  const int l16  = lane & 15;
  const int kg   = lane >> 4;

  f32x4 acc[2][2] = {};

  bf16x8 ra[4], rb;
  #pragma unroll
  for (int i = 0; i < 4; ++i) {
    int it = tid + i * 256;
    ra[i] = load8(kps, (size_t)(m0 + (it >> 3)) * KPSZ + (it & 7) * 8, b16);
  }
  rb = load8(W, (size_t)(n0 + (tid >> 3)) * KPSZ + (tid & 7) * 8, b16);

  for (int s = 0; s < KPSZ / BK; ++s) {
    __syncthreads();
    #pragma unroll
    for (int i = 0; i < 4; ++i) {
      int it = tid + i * 256;
      *(bf16x8*)(sA + sw(it >> 3, (it & 7) * 8)) = ra[i];
    }
    *(bf16x8*)(sB + sw(tid >> 3, (tid & 7) * 8)) = rb;
    __syncthreads();

    if (s + 1 < KPSZ / BK) {
      int k0 = (s + 1) * BK;
      #pragma unroll
      for (int i = 0; i < 4; ++i) {
        int it = tid + i * 256;
        ra[i] = load8(kps, (size_t)(m0 + (it >> 3)) * KPSZ + k0 + (it & 7) * 8, b16);
      }
      rb = load8(W, (size_t)(n0 + (tid >> 3)) * KPSZ + k0 + (tid & 7) * 8, b16);
    }

    #pragma unroll
    for (int ks = 0; ks < 2; ++ks) {
      bf16x8 a[2], b[2];
      #pragma unroll
      for (int mi = 0; mi < 2; ++mi) {
        int row = wave * 32 + mi * 16 + l16;
        a[mi] = *(const bf16x8*)(sA + sw(row, ks * 32 + kg * 8));
      }
      #pragma unroll
      for (int ni = 0; ni < 2; ++ni) {
        int row = ni * 16 + l16;
        b[ni] = *(const bf16x8*)(sB + sw(row, ks * 32 + kg * 8));
      }
      #pragma unroll
      for (int mi = 0; mi < 2; ++mi)
        #pragma unroll
        for (int ni = 0; ni < 2; ++ni)
          acc[mi][ni] = __builtin_amdgcn_mfma_f32_16x16x32_bf16(a[mi], b[ni], acc[mi][ni], 0, 0, 0);
    }
  }

  #pragma unroll
  for (int mi = 0; mi < 2; ++mi)
    #pragma unroll
    for (int r = 0; r < 4; ++r) {
      int m = m0 + wave * 32 + mi * 16 + kg * 4 + r;
      #pragma unroll
      for (int ni = 0; ni < 2; ++ni) {
        int n = n0 + ni * 16 + l16;
        stg1(out, (size_t)m * KPSZ + n, acc[mi][ni][r] + ldg1(bias, n, b16), b16);
      }
    }
}

struct CellArgs {
  const void *Ax, *Wih, *Ah, *Whh, *bih, *bhh, *Cprev;
  size_t hoff, h2off, coff;
  int Kx, dup;
};
struct Args3 {
  CellArgs c[3];
  void* outbase;
  const void* kps;
};

__global__ __launch_bounds__(256)
void lstm_cells_kernel(Args3 A) {
  __shared__ __align__(16) bf16 sA[BM * BK];
  __shared__ __align__(16) bf16 sW[4 * BNH * BK];

  const CellArgs p = A.c[blockIdx.z];
  const bool b16 = detect_b16(A.kps);
  const int n0   = blockIdx.x * BNH;
  const int m0   = blockIdx.y * BM;
  const int tid  = threadIdx.x;
  const int wave = tid >> 6;
  const int lane = tid & 63;
  const int l16  = lane & 15;
  const int kg   = lane >> 4;

  f32x4 acc[4][2][2] = {};

  const int steps1 = p.Kx / BK;
  const int steps  = steps1 + HID / BK;

  bf16x8 ra[4], rw[4];
  #pragma unroll
  for (int i = 0; i < 4; ++i) {
    int it = tid + i * 256;
    ra[i] = load8(p.Ax, (size_t)(m0 + (it >> 3)) * p.Kx + (it & 7) * 8, b16);
  }
  #pragma unroll
  for (int i = 0; i < 4; ++i) {
    int it = tid + i * 256;
    int rr = it >> 3;
    int grow = (rr >> 5) * HID + n0 + (rr & 31);
    rw[i] = load8(p.Wih, (size_t)grow * p.Kx + (it & 7) * 8, b16);
  }

  for (int s = 0; s < steps; ++s) {
    __syncthreads();
    #pragma unroll
    for (int i = 0; i < 4; ++i) {
      int it = tid + i * 256;
      *(bf16x8*)(sA + sw(it >> 3, (it & 7) * 8)) = ra[i];
    }
    #pragma unroll
    for (int i = 0; i < 4; ++i) {
      int it = tid + i * 256;
      *(bf16x8*)(sW + sw(it >> 3, (it & 7) * 8)) = rw[i];
    }
    __syncthreads();

    if (s + 1 < steps) {
      const void *A_, *W_; int K_, k0_;
      int s2 = s + 1;
      if (s2 < steps1) { A_ = p.Ax; W_ = p.Wih; K_ = p.Kx; k0_ = s2 * BK; }
      else             { A_ = p.Ah; W_ = p.Whh; K_ = HID;  k0_ = (s2 - steps1) * BK; }
      #pragma unroll
      for (int i = 0; i < 4; ++i) {
        int it = tid + i * 256;
        ra[i] = load8(A_, (size_t)(m0 + (it >> 3)) * K_ + k0_ + (it & 7) * 8, b16);
      }
      #pragma unroll
      for (int i = 0; i < 4; ++i) {
        int it = tid + i * 256;
        int rr = it >> 3;
        int grow = (rr >> 5) * HID + n0 + (rr & 31);
        rw[i] = load8(W_, (size_t)grow * K_ + k0_ + (it & 7) * 8, b16);
      }
    }

    #pragma unroll
    for (int ks = 0; ks < 2; ++ks) {
      bf16x8 a[2], b[4][2];
      #pragma unroll
      for (int mi = 0; mi < 2; ++mi) {
        int row = wave * 32 + mi * 16 + l16;
        a[mi] = *(const bf16x8*)(sA + sw(row, ks * 32 + kg * 8));
      }
      #pragma unroll
      for (int g = 0; g < 4; ++g)
        #pragma unroll
        for (int ni = 0; ni < 2; ++ni) {
          int row = g * 32 + ni * 16 + l16;
          b[g][ni] = *(const bf16x8*)(sW + sw(row, ks * 32 + kg * 8));
        }
      #pragma unroll
      for (int g = 0; g < 4; ++g)
        #pragma unroll
        for (int mi = 0; mi < 2; ++mi)
          #pragma unroll
          for (int ni = 0; ni < 2; ++ni)
            acc[g][mi][ni] = __builtin_amdgcn_mfma_f32_16x16x32_bf16(
                a[mi], b[g][ni], acc[g][mi][ni], 0, 0, 0);
    }
  }

  float bsum[4][2];
  #pragma unroll
  for (int g = 0; g < 4; ++g)
    #pragma unroll
    for (int ni = 0; ni < 2; ++ni) {
      int n = n0 + ni * 16 + l16;
      bsum[g][ni] = ldg1(p.bih, g * HID + n, b16) + ldg1(p.bhh, g * HID + n, b16);
    }

  #pragma unroll
  for (int mi = 0; mi < 2; ++mi)
    #pragma unroll
    for (int r = 0; r < 4; ++r) {
      int m = m0 + wave * 32 + mi * 16 + kg * 4 + r;
      size_t rowoff = (size_t)m * HID;
      #pragma unroll
      for (int ni = 0; ni < 2; ++ni) {
        int n = n0 + ni * 16 + l16;
        float xi = acc[0][mi][ni][r] + bsum[0][ni];
        float xf = acc[1][mi][ni][r] + bsum[1][ni];
        float xg = acc[2][mi][ni][r] + bsum[2][ni];
        float xo = acc[3][mi][ni][r] + bsum[3][ni];
        float I = sigm(xi);
        float F = sigm(xf);
        float G = tanhx(xg);
        float O = sigm(xo);
        float c  = ldg1(p.Cprev, rowoff + n, b16);
        float cn = F * c + I * G;
        float hn = O * tanhx(cn);
        stg1(A.outbase, p.coff + rowoff + n, cn, b16);
        stg1(A.outbase, p.hoff + rowoff + n, hn, b16);
        if (p.dup) stg1(A.outbase, p.h2off + rowoff + n, hn, b16);
      }
    }
}

// ======================= prep: bf16 ws + emb GEMM ==========================

#define NSEG 9

struct PrepArgs {
  const void* src[NSEG];
  bf16*       dst[NSEG];
  unsigned    pre[NSEG + 1];
  const void* kps;
  const void* W_emb;
  const void* b_emb;
  bf16*       in_frame;
  int         nconv;
};

__global__ __launch_bounds__(256)
void prep_kernel(PrepArgs P) {
  const bool b16 = detect_b16(P.kps);
  const int tid = threadIdx.x;
  const int bid = blockIdx.x;

  if (bid < 256) {
    __shared__ __align__(16) bf16 sA[BM * BK];
    __shared__ __align__(16) bf16 sB[BNH * BK];
    const int n0   = (bid & 7) * BNH;
    const int m0   = (bid >> 3) * BM;
    const int wave = tid >> 6;
    const int lane = tid & 63;
    const int l16  = lane & 15;
    const int kg   = lane >> 4;

    f32x4 acc[2][2] = {};
    bf16x8 ra[4], rb;
    #pragma unroll
    for (int i = 0; i < 4; ++i) {
      int it = tid + i * 256;
      ra[i] = load8(P.kps, (size_t)(m0 + (it >> 3)) * KPSZ + (it & 7) * 8, b16);
    }
    rb = load8(P.W_emb, (size_t)(n0 + (tid >> 3)) * KPSZ + (tid & 7) * 8, b16);

    for (int s = 0; s < KPSZ / BK; ++s) {
      __syncthreads();
      #pragma unroll
      for (int i = 0; i < 4; ++i) {
        int it = tid + i * 256;
        *(bf16x8*)(sA + sw(it >> 3, (it & 7) * 8)) = ra[i];
      }
      *(bf16x8*)(sB + sw(tid >> 3, (tid & 7) * 8)) = rb;
      __syncthreads();

      if (s + 1 < KPSZ / BK) {
        int k0 = (s + 1) * BK;
        #pragma unroll
        for (int i = 0; i < 4; ++i) {
          int it = tid + i * 256;
          ra[i] = load8(P.kps, (size_t)(m0 + (it >> 3)) * KPSZ + k0 + (it & 7) * 8, b16);
        }
        rb = load8(P.W_emb, (size_t)(n0 + (tid >> 3)) * KPSZ + k0 + (tid & 7) * 8, b16);
      }

      #pragma unroll
      for (int ks = 0; ks < 2; ++ks) {
        bf16x8 a[2], bfr[2];
        #pragma unroll
        for (int mi = 0; mi < 2; ++mi) {
          int row = wave * 32 + mi * 16 + l16;
          a[mi] = *(const bf16x8*)(sA + sw(row, ks * 32 + kg * 8));
        }
        #pragma unroll
        for (int ni = 0; ni < 2; ++ni) {
          int row = ni * 16 + l16;
          bfr[ni] = *(const bf16x8*)(sB + sw(row, ks * 32 + kg * 8));
        }
        #pragma unroll
        for (int mi = 0; mi < 2; ++mi)
          #pragma unroll
          for (int ni = 0; ni < 2; ++ni)
            acc[mi][ni] = __builtin_amdgcn_mfma_f32_16x16x32_bf16(a[mi], bfr[ni], acc[mi][ni], 0, 0, 0);
      }
    }

    #pragma unroll
    for (int mi = 0; mi < 2; ++mi)
      #pragma unroll
      for (int r = 0; r < 4; ++r) {
        int m = m0 + wave * 32 + mi * 16 + kg * 4 + r;
        #pragma unroll
        for (int ni = 0; ni < 2; ++ni) {
          int n = n0 + ni * 16 + l16;
          P.in_frame[(size_t)m * KPSZ + n] = (bf16)(acc[mi][ni][r] + ldg1(P.b_emb, n, b16));
        }
      }
    return;
  }

  const int cb = bid - 256;
  const unsigned tot = P.pre[NSEG];
  const unsigned stride = (unsigned)P.nconv * 256u;
  for (unsigned c = (unsigned)cb * 256u + (unsigned)tid; c < tot; c += stride) {
    int s = 0;
    #pragma unroll
    for (int k = 0; k < NSEG - 1; ++k) s += (c >= P.pre[k + 1]) ? 1 : 0;
    unsigned lc = c - P.pre[s];
    bf16x8 v = load8(P.src[s], (size_t)lc * 8, b16);
    *(bf16x8*)(P.dst[s] + (size_t)lc * 8) = v;
  }
}

// ============== NEW fast path: 256-tile, 8-wave, pipelined =================
// Tile: 256 m-rows x (4 gates x 64 h-cols). 8 waves in 2m x 4n.
// Wave (wm,wn): rows wm*128 + mi*16 (mi 0..7), h-cols n0 + wn*16 + l16,
// all 4 gates (n-frag f = wn + 4*g -> gate g, same h-block wn) -> fused
// LSTM epilogue stays per-wave-local.
// Pipeline: at tile v start, issue all 8 global_load_lds for tile v+1 into
// buf[(v+1)&1] (its previous readers passed the prior __syncthreads -> safe);
// compute tile v from buf[v&1] in 2 phases (16 MFMA each, setprio-wrapped,
// raw s_barrier between); one __syncthreads (vmcnt0 drain, ~free: loads had
// a full tile of compute to land) per tile.
// LDS swizzle (rule #21: linear gl_lds dest + inverse-permuted global source
// + same XOR on read): col8 ^= (row>>1)&3 -> 2-way banks (free, m136).

struct NCell {
  const bf16 *Ax, *Wih, *Ah, *Whh;  // bf16 (workspace)
  const void *bih, *bhh, *Cprev;    // original dtype
  size_t hoff, h2off, coff;
  int Kx, dup;
};
struct NArgs {
  NCell c[3];
  void* outbase;
  const void* kps;
};

// stage one K-tile (A: 256x32, W: 256x32) -> 8 gl16 per thread-group
__device__ __forceinline__ void stage_tile2(const bf16* A_, const bf16* W_,
                                            int K_, int k0_, int m0, int n0,
                                            bf16* sa, bf16* swk,
                                            int w, int lane) {
  #pragma unroll
  for (int j = 0; j < 2; ++j) {
    int c0 = (j * 8 + w) * 64;     // wave-uniform chunk base
    int c  = c0 + lane;
    int row = c >> 2, col8 = c & 3;
    int gc  = col8 ^ ((row >> 1) & 3);   // inverse swizzle on global source
    gl16(A_ + (size_t)(m0 + row) * K_ + k0_ + gc * 8, sa + c0 * 8);
  }
  #pragma unroll
  for (int j = 0; j < 2; ++j) {
    int c0 = (j * 8 + w) * 64;
    int c  = c0 + lane;
    int row = c >> 2, col8 = c & 3;
    int gc  = col8 ^ ((row >> 1) & 3);
    int wrow = (row >> 6) * HID + n0 + (row & 63);   // gate-gathered W row
    gl16(W_ + (size_t)wrow * K_ + k0_ + gc * 8, swk + c0 * 8);
  }
}

__global__ __launch_bounds__(512, 2)
void lstm_fast_kernel(NArgs Ar) {
  __shared__ __align__(16) bf16 sA[2][BM2 * BK2];   // 2 x 16 KB
  __shared__ __align__(16) bf16 sW[2][4 * BN2 * BK2];  // 2 x 16 KB

  const NCell p = Ar.c[blockIdx.z];
  const bool b16 = detect_b16(Ar.kps);
  const int n0   = blockIdx.x * BN2;
  const int m0   = blockIdx.y * BM2;
  const int tid  = threadIdx.x;
  const int w    = tid >> 6;
  const int lane = tid & 63;
  const int l16  = lane & 15;
  const int kg   = lane >> 4;
  const int wm   = w >> 2;
  const int wn   = w & 3;

  f32x4 acc[4][8] = {};   // [gate][mi]

  const int s1 = p.Kx / BK2;
  const int nt = s1 + HID / BK2;

  // prologue: stage tile 0
  stage_tile2(p.Ax, p.Wih, p.Kx, 0, m0, n0, sA[0], sW[0], w, lane);
  __syncthreads();   // vmcnt(0): tile 0 ready

  for (int v = 0; v < nt; ++v) {
    // issue next tile's loads into the other buffer (prev readers passed
    // the last __syncthreads -> safe to overwrite any time from here on)
    if (v + 1 < nt) {
      const bf16 *A_, *W_; int K_, k0_;
      int v2 = v + 1;
      if (v2 < s1) { A_ = p.Ax; W_ = p.Wih; K_ = p.Kx; k0_ = v2 * BK2; }
      else         { A_ = p.Ah; W_ = p.Whh; K_ = HID;  k0_ = (v2 - s1) * BK2; }
      stage_tile2(A_, W_, K_, k0_, m0, n0, sA[v2 & 1], sW[v2 & 1], w, lane);
    }

    const bf16* sa = sA[v & 1];
    const bf16* sw_ = sW[v & 1];

    // B fragments (persist across both phases)
    bf16x8 b[4];
    #pragma unroll
    for (int g = 0; g < 4; ++g) {
      int rb = g * 64 + wn * 16 + l16;
      b[g] = *(const bf16x8*)(sw_ + rb * BK2 + ((kg ^ ((rb >> 1) & 3)) * 8));
    }

    // phase 0: mi 0..3
    {
      bf16x8 a[4];
      #pragma unroll
      for (int mi = 0; mi < 4; ++mi) {
        int ra = wm * 128 + mi * 16 + l16;
        a[mi] = *(const bf16x8*)(sa + ra * BK2 + ((kg ^ ((ra >> 1) & 3)) * 8));
      }
      __builtin_amdgcn_s_setprio(1);
      #pragma unroll
      for (int g = 0; g < 4; ++g)
        #pragma unroll
        for (int mi = 0; mi < 4; ++mi)
          acc[g][mi] = __builtin_amdgcn_mfma_f32_16x16x32_bf16(a[mi], b[g], acc[g][mi], 0, 0, 0);
      __builtin_amdgcn_s_setprio(0);
    }
    __builtin_amdgcn_s_barrier();   // phase alignment only (no data dep)

    // phase 1: mi 4..7
    {
      bf16x8 a[4];
      #pragma unroll
      for (int mi = 0; mi < 4; ++mi) {
        int ra = wm * 128 + (mi + 4) * 16 + l16;
        a[mi] = *(const bf16x8*)(sa + ra * BK2 + ((kg ^ ((ra >> 1) & 3)) * 8));
      }
      __builtin_amdgcn_s_setprio(1);
      #pragma unroll
      for (int g = 0; g < 4; ++g)
        #pragma unroll
        for (int mi = 0; mi < 4; ++mi)
          acc[g][mi + 4] = __builtin_amdgcn_mfma_f32_16x16x32_bf16(a[mi], b[g], acc[g][mi + 4], 0, 0, 0);
      __builtin_amdgcn_s_setprio(0);
    }

    __syncthreads();   // vmcnt(0)+lgkmcnt(0)+barrier: tile v+1 landed,
                       // all reads of buf[v&1] done before it is re-staged
  }

  // ---- epilogue: per-lane LSTM cell update --------------------------------
  const int n = n0 + wn * 16 + l16;
  float bsum[4];
  #pragma unroll
  for (int g = 0; g < 4; ++g)
    bsum[g] = ldg1(p.bih, g * HID + n, b16) + ldg1(p.bhh, g * HID + n, b16);

  #pragma unroll
  for (int mi = 0; mi < 8; ++mi)
    #pragma unroll
    for (int r = 0; r < 4; ++r) {
      int m = m0 + wm * 128 + mi * 16 + kg * 4 + r;
      size_t rowoff = (size_t)m * HID;
      float xi = acc[0][mi][r] + bsum[0];
      float xf = acc[1][mi][r] + bsum[1];
      float xg = acc[2][mi][r] + bsum[2];
      float xo = acc[3][mi][r] + bsum[3];
      float I = sigm(xi);
      float F = sigm(xf);
      float G = tanhx(xg);
      float O = sigm(xo);
      float c  = ldg1(p.Cprev, rowoff + n, b16);
      float cn = F * c + I * G;
      float hn = O * tanhx(cn);
      stg1(Ar.outbase, p.coff + rowoff + n, cn, b16);
      stg1(Ar.outbase, p.hoff + rowoff + n, hn, b16);
      if (p.dup) stg1(Ar.outbase, p.h2off + rowoff + n, hn, b16);
    }
}

extern "C" void kernel_launch(void* const* d_in, const int* in_sizes, int n_in,
                              void* d_out, int out_size, void* d_ws, size_t ws_size,
                              hipStream_t stream) {
  const void* kps   = d_in[0];
  const void* h0    = d_in[1];
  const void* h1    = d_in[2];
  const void* h2    = d_in[3];
  const void* c0    = d_in[4];
  const void* c1    = d_in[5];
  const void* c2    = d_in[6];
  const void* W_emb = d_in[7];
  const void* b_emb = d_in[8];
  const void* w_ih1 = d_in[9];
  const void* w_hh1 = d_in[10];
  const void* b_ih1 = d_in[11];
  const void* b_hh1 = d_in[12];
  const void* w_ih2 = d_in[13];
  const void* w_hh2 = d_in[14];
  const void* b_ih2 = d_in[15];
  const void* b_hh2 = d_in[16];
  const void* w_ih3 = d_in[17];
  const void* w_hh3 = d_in[18];
  const void* b_ih3 = d_in[19];
  const void* b_hh3 = d_in[20];

  const size_t S = (size_t)B_DIM * HID;

  const size_t E_SMALL = (size_t)4 * HID * KPSZ;     // 1,048,576
  const size_t E_BIG   = (size_t)4 * HID * HID;      // 4,194,304
  const size_t TOT_ELEMS = 2 * E_SMALL + 8 * E_BIG;  // 35,651,584
  const size_t NEED = TOT_ELEMS * 2;                 // 71,303,168 B

  if (ws_size >= NEED) {
    bf16* wsb      = (bf16*)d_ws;
    bf16* in_frame = wsb;
    bf16* W1x      = wsb + E_SMALL;
    bf16* W1h      = W1x + E_SMALL;
    bf16* W2x      = W1h + E_BIG;
    bf16* W2h      = W2x + E_BIG;
    bf16* W3x      = W2h + E_BIG;
    bf16* W3h      = W3x + E_BIG;
    bf16* H0       = W3h + E_BIG;
    bf16* H1       = H0 + E_BIG;
    bf16* H2       = H1 + E_BIG;

    PrepArgs P;
    const void* srcs[NSEG] = { w_ih1, w_hh1, w_ih2, w_hh2, w_ih3, w_hh3, h0, h1, h2 };
    bf16*       dsts[NSEG] = { W1x,   W1h,   W2x,   W2h,   W3x,   W3h,  H0, H1, H2 };
    unsigned    cnts[NSEG] = { (unsigned)(E_SMALL / 8), (unsigned)(E_BIG / 8),
                               (unsigned)(E_BIG / 8),   (unsigned)(E_BIG / 8),
                               (unsigned)(E_BIG / 8),   (unsigned)(E_BIG / 8),
                               (unsigned)(E_BIG / 8),   (unsigned)(E_BIG / 8),
                               (unsigned)(E_BIG / 8) };
    unsigned acc = 0;
    for (int i = 0; i < NSEG; ++i) {
      P.src[i] = srcs[i];
      P.dst[i] = dsts[i];
      P.pre[i] = acc;
      acc += cnts[i];
    }
    P.pre[NSEG] = acc;
    P.kps = kps; P.W_emb = W_emb; P.b_emb = b_emb; P.in_frame = in_frame;
    P.nconv = 2048;

    prep_kernel<<<dim3(256 + 2048), 256, 0, stream>>>(P);

    NArgs N;
    N.outbase = d_out;
    N.kps = kps;
    N.c[0] = { in_frame, W1x, H0, W1h, b_ih1, b_hh1, c0, 1 * S, 0, 4 * S, KPSZ, 0 };
    N.c[1] = { H0,       W2x, H1, W2h, b_ih2, b_hh2, c1, 2 * S, 0, 5 * S, HID,  0 };
    N.c[2] = { H1,       W3x, H2, W3h, b_ih3, b_hh3, c2, 0,     3 * S, 6 * S, HID, 1 };

    lstm_fast_kernel<<<dim3(HID / BN2, B_DIM / BM2, 3), 512, 0, stream>>>(N);
    return;
  }

  // -------- fallback: previous verified path --------
  void* in_frame = d_ws;
  emb_kernel<<<dim3(KPSZ / BNH, B_DIM / BM), 256, 0, stream>>>(kps, W_emb, b_emb, in_frame);

  Args3 A;
  A.outbase = d_out;
  A.kps = kps;
  A.c[0] = { in_frame, w_ih1, h0, w_hh1, b_ih1, b_hh1, c0,
             1 * S, 0, 4 * S, KPSZ, 0 };
  A.c[1] = { h0, w_ih2, h1, w_hh2, b_ih2, b_hh2, c1,
             2 * S, 0, 5 * S, HID, 0 };
  A.c[2] = { h1, w_ih3, h2, w_hh3, b_ih3, b_hh3, c2,
             0 * S, 3 * S, 6 * S, HID, 1 };

  lstm_cells_kernel<<<dim3(HID / BNH, B_DIM / BM, 3), 256, 0, stream>>>(A);
}

// Round 4
// 512.928 us; speedup vs baseline: 1.1025x; 1.1025x over previous
//
#include <hip/hip_runtime.h>
#include <stdint.h>

typedef __bf16 bf16;
typedef __bf16 bf16x8 __attribute__((ext_vector_type(8)));
typedef float f32x4 __attribute__((ext_vector_type(4)));

#define B_DIM 4096
#define HID   1024
#define KPSZ  256

#define BM  128   // fallback m-tile
#define BNH 32    // fallback n-tile within H
#define BK  64    // fallback k-step

#define BK3 32    // new-path k-step

// ---- runtime dtype detection (unchanged from passing round) --------------
__device__ __forceinline__ bool detect_b16(const void* kps) {
  const uint16_t* k16 = (const uint16_t*)kps;
  int lane = threadIdx.x & 63;
  int c = 0;
#pragma unroll
  for (int j = 0; j < 8; ++j) {
    uint16_t v = k16[(lane * 8 + j) * 2];
    int e = (v >> 7) & 0xFF;
    c += (e >= 100 && e <= 140) ? 1 : 0;
  }
#pragma unroll
  for (int s = 1; s < 64; s <<= 1) c += __shfl_xor(c, s, 64);
  return c > 256;
}

__device__ __forceinline__ bf16x8 load8(const void* base, size_t off, bool b16) {
  if (b16) {
    return *(const bf16x8*)((const bf16*)base + off);
  } else {
    const float* f = (const float*)base + off;
    float4 lo = *(const float4*)f;
    float4 hi = *(const float4*)(f + 4);
    bf16x8 r;
    r[0] = (bf16)lo.x; r[1] = (bf16)lo.y; r[2] = (bf16)lo.z; r[3] = (bf16)lo.w;
    r[4] = (bf16)hi.x; r[5] = (bf16)hi.y; r[6] = (bf16)hi.z; r[7] = (bf16)hi.w;
    return r;
  }
}
__device__ __forceinline__ float ldg1(const void* p, size_t i, bool b16) {
  return b16 ? (float)((const bf16*)p)[i] : ((const float*)p)[i];
}
__device__ __forceinline__ void stg1(void* p, size_t i, float v, bool b16) {
  if (b16) ((bf16*)p)[i] = (bf16)v;
  else     ((float*)p)[i] = v;
}

__device__ __forceinline__ float sigm(float x) {
  return 1.0f / (1.0f + __expf(-x));
}
__device__ __forceinline__ float tanhx(float x) {
  float e = __expf(-2.0f * fabsf(x));
  float t = (1.0f - e) / (1.0f + e);
  return x < 0.0f ? -t : t;
}

// XOR-swizzled LDS index (fallback + emb kernels, BK=64 rows)
__device__ __forceinline__ int sw(int row, int col8) {
  return row * BK + (col8 ^ ((row & 7) << 3));
}

// async global->LDS, 16B per lane; dest base must be wave-uniform
__device__ __forceinline__ void gl16(const bf16* g, bf16* l) {
  __builtin_amdgcn_global_load_lds(
      (const __attribute__((address_space(1))) void*)g,
      (__attribute__((address_space(3))) void*)l, 16, 0, 0);
}

// ======================= OLD PATH (fallback, verified) =====================

__global__ __launch_bounds__(256)
void emb_kernel(const void* __restrict__ kps, const void* __restrict__ W,
                const void* __restrict__ bias, void* __restrict__ out) {
  __shared__ __align__(16) bf16 sA[BM * BK];   // 16 KB
  __shared__ __align__(16) bf16 sB[BNH * BK];  // 4 KB

  const bool b16 = detect_b16(kps);
  const int n0   = blockIdx.x * BNH;
  const int m0   = blockIdx.y * BM;
  const int tid  = threadIdx.x;
  const int wave = tid >> 6;
  const int lane = tid & 63;
  const int l16  = lane & 15;
  const int kg   = lane >> 4;

  f32x4 acc[2][2] = {};

  bf16x8 ra[4], rb;
  #pragma unroll
  for (int i = 0; i < 4; ++i) {
    int it = tid + i * 256;
    ra[i] = load8(kps, (size_t)(m0 + (it >> 3)) * KPSZ + (it & 7) * 8, b16);
  }
  rb = load8(W, (size_t)(n0 + (tid >> 3)) * KPSZ + (tid & 7) * 8, b16);

  for (int s = 0; s < KPSZ / BK; ++s) {
    __syncthreads();
    #pragma unroll
    for (int i = 0; i < 4; ++i) {
      int it = tid + i * 256;
      *(bf16x8*)(sA + sw(it >> 3, (it & 7) * 8)) = ra[i];
    }
    *(bf16x8*)(sB + sw(tid >> 3, (tid & 7) * 8)) = rb;
    __syncthreads();

    if (s + 1 < KPSZ / BK) {
      int k0 = (s + 1) * BK;
      #pragma unroll
      for (int i = 0; i < 4; ++i) {
        int it = tid + i * 256;
        ra[i] = load8(kps, (size_t)(m0 + (it >> 3)) * KPSZ + k0 + (it & 7) * 8, b16);
      }
      rb = load8(W, (size_t)(n0 + (tid >> 3)) * KPSZ + k0 + (tid & 7) * 8, b16);
    }

    #pragma unroll
    for (int ks = 0; ks < 2; ++ks) {
      bf16x8 a[2], b[2];
      #pragma unroll
      for (int mi = 0; mi < 2; ++mi) {
        int row = wave * 32 + mi * 16 + l16;
        a[mi] = *(const bf16x8*)(sA + sw(row, ks * 32 + kg * 8));
      }
      #pragma unroll
      for (int ni = 0; ni < 2; ++ni) {
        int row = ni * 16 + l16;
        b[ni] = *(const bf16x8*)(sB + sw(row, ks * 32 + kg * 8));
      }
      #pragma unroll
      for (int mi = 0; mi < 2; ++mi)
        #pragma unroll
        for (int ni = 0; ni < 2; ++ni)
          acc[mi][ni] = __builtin_amdgcn_mfma_f32_16x16x32_bf16(a[mi], b[ni], acc[mi][ni], 0, 0, 0);
    }
  }

  #pragma unroll
  for (int mi = 0; mi < 2; ++mi)
    #pragma unroll
    for (int r = 0; r < 4; ++r) {
      int m = m0 + wave * 32 + mi * 16 + kg * 4 + r;
      #pragma unroll
      for (int ni = 0; ni < 2; ++ni) {
        int n = n0 + ni * 16 + l16;
        stg1(out, (size_t)m * KPSZ + n, acc[mi][ni][r] + ldg1(bias, n, b16), b16);
      }
    }
}

struct CellArgs {
  const void *Ax, *Wih, *Ah, *Whh, *bih, *bhh, *Cprev;
  size_t hoff, h2off, coff;
  int Kx, dup;
};
struct Args3 {
  CellArgs c[3];
  void* outbase;
  const void* kps;
};

__global__ __launch_bounds__(256)
void lstm_cells_kernel(Args3 A) {
  __shared__ __align__(16) bf16 sA[BM * BK];
  __shared__ __align__(16) bf16 sW[4 * BNH * BK];

  const CellArgs p = A.c[blockIdx.z];
  const bool b16 = detect_b16(A.kps);
  const int n0   = blockIdx.x * BNH;
  const int m0   = blockIdx.y * BM;
  const int tid  = threadIdx.x;
  const int wave = tid >> 6;
  const int lane = tid & 63;
  const int l16  = lane & 15;
  const int kg   = lane >> 4;

  f32x4 acc[4][2][2] = {};

  const int steps1 = p.Kx / BK;
  const int steps  = steps1 + HID / BK;

  bf16x8 ra[4], rw[4];
  #pragma unroll
  for (int i = 0; i < 4; ++i) {
    int it = tid + i * 256;
    ra[i] = load8(p.Ax, (size_t)(m0 + (it >> 3)) * p.Kx + (it & 7) * 8, b16);
  }
  #pragma unroll
  for (int i = 0; i < 4; ++i) {
    int it = tid + i * 256;
    int rr = it >> 3;
    int grow = (rr >> 5) * HID + n0 + (rr & 31);
    rw[i] = load8(p.Wih, (size_t)grow * p.Kx + (it & 7) * 8, b16);
  }

  for (int s = 0; s < steps; ++s) {
    __syncthreads();
    #pragma unroll
    for (int i = 0; i < 4; ++i) {
      int it = tid + i * 256;
      *(bf16x8*)(sA + sw(it >> 3, (it & 7) * 8)) = ra[i];
    }
    #pragma unroll
    for (int i = 0; i < 4; ++i) {
      int it = tid + i * 256;
      *(bf16x8*)(sW + sw(it >> 3, (it & 7) * 8)) = rw[i];
    }
    __syncthreads();

    if (s + 1 < steps) {
      const void *A_, *W_; int K_, k0_;
      int s2 = s + 1;
      if (s2 < steps1) { A_ = p.Ax; W_ = p.Wih; K_ = p.Kx; k0_ = s2 * BK; }
      else             { A_ = p.Ah; W_ = p.Whh; K_ = HID;  k0_ = (s2 - steps1) * BK; }
      #pragma unroll
      for (int i = 0; i < 4; ++i) {
        int it = tid + i * 256;
        ra[i] = load8(A_, (size_t)(m0 + (it >> 3)) * K_ + k0_ + (it & 7) * 8, b16);
      }
      #pragma unroll
      for (int i = 0; i < 4; ++i) {
        int it = tid + i * 256;
        int rr = it >> 3;
        int grow = (rr >> 5) * HID + n0 + (rr & 31);
        rw[i] = load8(W_, (size_t)grow * K_ + k0_ + (it & 7) * 8, b16);
      }
    }

    #pragma unroll
    for (int ks = 0; ks < 2; ++ks) {
      bf16x8 a[2], b[4][2];
      #pragma unroll
      for (int mi = 0; mi < 2; ++mi) {
        int row = wave * 32 + mi * 16 + l16;
        a[mi] = *(const bf16x8*)(sA + sw(row, ks * 32 + kg * 8));
      }
      #pragma unroll
      for (int g = 0; g < 4; ++g)
        #pragma unroll
        for (int ni = 0; ni < 2; ++ni) {
          int row = g * 32 + ni * 16 + l16;
          b[g][ni] = *(const bf16x8*)(sW + sw(row, ks * 32 + kg * 8));
        }
      #pragma unroll
      for (int g = 0; g < 4; ++g)
        #pragma unroll
        for (int mi = 0; mi < 2; ++mi)
          #pragma unroll
          for (int ni = 0; ni < 2; ++ni)
            acc[g][mi][ni] = __builtin_amdgcn_mfma_f32_16x16x32_bf16(
                a[mi], b[g][ni], acc[g][mi][ni], 0, 0, 0);
    }
  }

  float bsum[4][2];
  #pragma unroll
  for (int g = 0; g < 4; ++g)
    #pragma unroll
    for (int ni = 0; ni < 2; ++ni) {
      int n = n0 + ni * 16 + l16;
      bsum[g][ni] = ldg1(p.bih, g * HID + n, b16) + ldg1(p.bhh, g * HID + n, b16);
    }

  #pragma unroll
  for (int mi = 0; mi < 2; ++mi)
    #pragma unroll
    for (int r = 0; r < 4; ++r) {
      int m = m0 + wave * 32 + mi * 16 + kg * 4 + r;
      size_t rowoff = (size_t)m * HID;
      #pragma unroll
      for (int ni = 0; ni < 2; ++ni) {
        int n = n0 + ni * 16 + l16;
        float xi = acc[0][mi][ni][r] + bsum[0][ni];
        float xf = acc[1][mi][ni][r] + bsum[1][ni];
        float xg = acc[2][mi][ni][r] + bsum[2][ni];
        float xo = acc[3][mi][ni][r] + bsum[3][ni];
        float I = sigm(xi);
        float F = sigm(xf);
        float G = tanhx(xg);
        float O = sigm(xo);
        float c  = ldg1(p.Cprev, rowoff + n, b16);
        float cn = F * c + I * G;
        float hn = O * tanhx(cn);
        stg1(A.outbase, p.coff + rowoff + n, cn, b16);
        stg1(A.outbase, p.hoff + rowoff + n, hn, b16);
        if (p.dup) stg1(A.outbase, p.h2off + rowoff + n, hn, b16);
      }
    }
}

// ======================= prep: bf16 ws + emb GEMM ==========================

#define NSEG 9

struct PrepArgs {
  const void* src[NSEG];
  bf16*       dst[NSEG];
  unsigned    pre[NSEG + 1];
  const void* kps;
  const void* W_emb;
  const void* b_emb;
  bf16*       in_frame;
  int         nconv;
};

__global__ __launch_bounds__(256)
void prep_kernel(PrepArgs P) {
  const bool b16 = detect_b16(P.kps);
  const int tid = threadIdx.x;
  const int bid = blockIdx.x;

  if (bid < 256) {
    __shared__ __align__(16) bf16 sA[BM * BK];
    __shared__ __align__(16) bf16 sB[BNH * BK];
    const int n0   = (bid & 7) * BNH;
    const int m0   = (bid >> 3) * BM;
    const int wave = tid >> 6;
    const int lane = tid & 63;
    const int l16  = lane & 15;
    const int kg   = lane >> 4;

    f32x4 acc[2][2] = {};
    bf16x8 ra[4], rb;
    #pragma unroll
    for (int i = 0; i < 4; ++i) {
      int it = tid + i * 256;
      ra[i] = load8(P.kps, (size_t)(m0 + (it >> 3)) * KPSZ + (it & 7) * 8, b16);
    }
    rb = load8(P.W_emb, (size_t)(n0 + (tid >> 3)) * KPSZ + (tid & 7) * 8, b16);

    for (int s = 0; s < KPSZ / BK; ++s) {
      __syncthreads();
      #pragma unroll
      for (int i = 0; i < 4; ++i) {
        int it = tid + i * 256;
        *(bf16x8*)(sA + sw(it >> 3, (it & 7) * 8)) = ra[i];
      }
      *(bf16x8*)(sB + sw(tid >> 3, (tid & 7) * 8)) = rb;
      __syncthreads();

      if (s + 1 < KPSZ / BK) {
        int k0 = (s + 1) * BK;
        #pragma unroll
        for (int i = 0; i < 4; ++i) {
          int it = tid + i * 256;
          ra[i] = load8(P.kps, (size_t)(m0 + (it >> 3)) * KPSZ + k0 + (it & 7) * 8, b16);
        }
        rb = load8(P.W_emb, (size_t)(n0 + (tid >> 3)) * KPSZ + k0 + (tid & 7) * 8, b16);
      }

      #pragma unroll
      for (int ks = 0; ks < 2; ++ks) {
        bf16x8 a[2], bfr[2];
        #pragma unroll
        for (int mi = 0; mi < 2; ++mi) {
          int row = wave * 32 + mi * 16 + l16;
          a[mi] = *(const bf16x8*)(sA + sw(row, ks * 32 + kg * 8));
        }
        #pragma unroll
        for (int ni = 0; ni < 2; ++ni) {
          int row = ni * 16 + l16;
          bfr[ni] = *(const bf16x8*)(sB + sw(row, ks * 32 + kg * 8));
        }
        #pragma unroll
        for (int mi = 0; mi < 2; ++mi)
          #pragma unroll
          for (int ni = 0; ni < 2; ++ni)
            acc[mi][ni] = __builtin_amdgcn_mfma_f32_16x16x32_bf16(a[mi], bfr[ni], acc[mi][ni], 0, 0, 0);
      }
    }

    #pragma unroll
    for (int mi = 0; mi < 2; ++mi)
      #pragma unroll
      for (int r = 0; r < 4; ++r) {
        int m = m0 + wave * 32 + mi * 16 + kg * 4 + r;
        #pragma unroll
        for (int ni = 0; ni < 2; ++ni) {
          int n = n0 + ni * 16 + l16;
          P.in_frame[(size_t)m * KPSZ + n] = (bf16)(acc[mi][ni][r] + ldg1(P.b_emb, n, b16));
        }
      }
    return;
  }

  const int cb = bid - 256;
  const unsigned tot = P.pre[NSEG];
  const unsigned stride = (unsigned)P.nconv * 256u;
  for (unsigned c = (unsigned)cb * 256u + (unsigned)tid; c < tot; c += stride) {
    int s = 0;
    #pragma unroll
    for (int k = 0; k < NSEG - 1; ++k) s += (c >= P.pre[k + 1]) ? 1 : 0;
    unsigned lc = c - P.pre[s];
    bf16x8 v = load8(P.src[s], (size_t)lc * 8, b16);
    *(bf16x8*)(P.dst[s] + (size_t)lc * 8) = v;
  }
}

// ========== NEW fast path: 128-tile, 4-wave, 3-buf ring, 2-deep ============
// Tile: 128 m-rows x (4 gates x 32 h-cols), K-step 32. 4 waves split m
// (wave w: rows w*32 + mi*16, mi<2; all 4 gates, ni<2 -> acc[4][2][2],
// 64 AGPR -> 3 waves/SIMD). LDS: 3 buffers x (A 8KB + W 8KB) = 48 KB ->
// 3 blocks/CU. Pipeline: at tile v issue tile v+2's 4 gl16 into
// buf[(v+2)%3]; s_waitcnt vmcnt(8) waits ONLY tile v's loads (2 full tile
// bodies of cover >> HBM latency); raw s_barrier; 10 ds_read_b128 + 16
// MFMA; s_barrier. Ring safety: buf[(v+2)%3]'s last readers (tile v-1)
// passed the end-barrier of tile v-1 before any wave reaches tile v's
// issue. Staging pointers precomputed per thread, advanced by BK3 elems
// per tile; h-phase switch resets them once (kills per-tile addr VALU).
// Swizzle (rule #21, both sides, r3-verified mapping): 16B-slot
// s' = s ^ ((row>>1)&3) -> 2-way banks (free).

struct NCell {
  const bf16 *Ax, *Wih, *Ah, *Whh;  // bf16 (workspace)
  const void *bih, *bhh, *Cprev;    // original dtype
  size_t hoff, h2off, coff;
  int Kx, dup;
};
struct NArgs {
  NCell c[3];
  void* outbase;
  const void* kps;
};

__global__ __launch_bounds__(256, 3)
void lstm_fast_kernel(NArgs Ar) {
  // [buf][ A: 128x32 | W: 128x32 ] bf16 -> 8192 elems (16 KB) per buffer
  __shared__ __align__(16) bf16 smem[3 * 8192];

  const NCell p = Ar.c[blockIdx.z];
  const bool b16 = detect_b16(Ar.kps);
  const int n0   = blockIdx.x * 32;
  const int m0   = blockIdx.y * 128;
  const int tid  = threadIdx.x;
  const int w    = tid >> 6;
  const int lane = tid & 63;
  const int l16  = lane & 15;
  const int kg   = lane >> 4;

  f32x4 acc[4][2][2] = {};

  const int s1 = p.Kx / BK3;
  const int nt = s1 + HID / BK3;

  // per-thread staging pointers: 2 chunks per matrix per tile.
  // chunk c: row = c>>2, slot s = c&3; global slot gc = s ^ ((row>>1)&3)
  const bf16 *pA0, *pA1, *pW0, *pW1, *hA0, *hA1, *hW0, *hW1;
  {
    int c0 = tid,       r0_ = c0 >> 2, g0_ = (c0 & 3) ^ ((r0_ >> 1) & 3);
    int c1 = tid + 256, r1_ = c1 >> 2, g1_ = (c1 & 3) ^ ((r1_ >> 1) & 3);
    pA0 = p.Ax + (size_t)(m0 + r0_) * p.Kx + g0_ * 8;
    pA1 = p.Ax + (size_t)(m0 + r1_) * p.Kx + g1_ * 8;
    hA0 = p.Ah + (size_t)(m0 + r0_) * HID + g0_ * 8;
    hA1 = p.Ah + (size_t)(m0 + r1_) * HID + g1_ * 8;
    int w0 = (r0_ >> 5) * HID + n0 + (r0_ & 31);   // 4 gates x 32 staged rows
    int w1 = (r1_ >> 5) * HID + n0 + (r1_ & 31);
    pW0 = p.Wih + (size_t)w0 * p.Kx + g0_ * 8;
    pW1 = p.Wih + (size_t)w1 * p.Kx + g1_ * 8;
    hW0 = p.Whh + (size_t)w0 * HID + g0_ * 8;
    hW1 = p.Whh + (size_t)w1 * HID + g1_ * 8;
  }
  // wave-uniform LDS chunk bases (elems): chunk base c0 = w*64 (+256)
  const int ldsO0 = w * 512;
  const int ldsO1 = w * 512 + 2048;

  auto issue = [&](int t, int b) {
    if (t == s1) { pA0 = hA0; pA1 = hA1; pW0 = hW0; pW1 = hW1; }
    bf16* d = smem + b * 8192;
    gl16(pA0, d + ldsO0);
    gl16(pA1, d + ldsO1);
    gl16(pW0, d + 4096 + ldsO0);
    gl16(pW1, d + 4096 + ldsO1);
    pA0 += BK3; pA1 += BK3; pW0 += BK3; pW1 += BK3;
  };

  issue(0, 0);
  issue(1, 1);

  int cb = 0;   // compute buffer = v % 3
  for (int v = 0; v < nt; ++v) {
    if (v + 2 < nt) {
      int ib = cb + 2; if (ib >= 3) ib -= 3;
      issue(v + 2, ib);
      asm volatile("s_waitcnt vmcnt(8)" ::: "memory");  // tile v's 4 done
    } else if (v + 1 < nt) {
      asm volatile("s_waitcnt vmcnt(4)" ::: "memory");
    } else {
      asm volatile("s_waitcnt vmcnt(0)" ::: "memory");
    }
    __builtin_amdgcn_s_barrier();        // tile v fully staged (all waves)
    asm volatile("" ::: "memory");

    const bf16* sa  = smem + cb * 8192;
    const bf16* sw_ = sa + 4096;

    bf16x8 a[2], b[4][2];
    #pragma unroll
    for (int mi = 0; mi < 2; ++mi) {
      int row = w * 32 + mi * 16 + l16;
      a[mi] = *(const bf16x8*)(sa + row * 32 + ((kg ^ ((row >> 1) & 3)) * 8));
    }
    #pragma unroll
    for (int g = 0; g < 4; ++g)
      #pragma unroll
      for (int ni = 0; ni < 2; ++ni) {
        int row = g * 32 + ni * 16 + l16;
        b[g][ni] = *(const bf16x8*)(sw_ + row * 32 + ((kg ^ ((row >> 1) & 3)) * 8));
      }
    #pragma unroll
    for (int g = 0; g < 4; ++g)
      #pragma unroll
      for (int mi = 0; mi < 2; ++mi)
        #pragma unroll
        for (int ni = 0; ni < 2; ++ni)
          acc[g][mi][ni] = __builtin_amdgcn_mfma_f32_16x16x32_bf16(
              a[mi], b[g][ni], acc[g][mi][ni], 0, 0, 0);

    asm volatile("" ::: "memory");
    __builtin_amdgcn_s_barrier();        // reads of buf cb done before reuse
    if (++cb == 3) cb = 0;
  }

  // ---- epilogue: per-lane LSTM cell update (r0-verified mapping) ----------
  float bsum[4][2];
  #pragma unroll
  for (int g = 0; g < 4; ++g)
    #pragma unroll
    for (int ni = 0; ni < 2; ++ni) {
      int n = n0 + ni * 16 + l16;
      bsum[g][ni] = ldg1(p.bih, g * HID + n, b16) + ldg1(p.bhh, g * HID + n, b16);
    }

  #pragma unroll
  for (int mi = 0; mi < 2; ++mi)
    #pragma unroll
    for (int r = 0; r < 4; ++r) {
      int m = m0 + w * 32 + mi * 16 + kg * 4 + r;
      size_t rowoff = (size_t)m * HID;
      #pragma unroll
      for (int ni = 0; ni < 2; ++ni) {
        int n = n0 + ni * 16 + l16;
        float xi = acc[0][mi][ni][r] + bsum[0][ni];
        float xf = acc[1][mi][ni][r] + bsum[1][ni];
        float xg = acc[2][mi][ni][r] + bsum[2][ni];
        float xo = acc[3][mi][ni][r] + bsum[3][ni];
        float I = sigm(xi);
        float F = sigm(xf);
        float G = tanhx(xg);
        float O = sigm(xo);
        float c  = ldg1(p.Cprev, rowoff + n, b16);
        float cn = F * c + I * G;
        float hn = O * tanhx(cn);
        stg1(Ar.outbase, p.coff + rowoff + n, cn, b16);
        stg1(Ar.outbase, p.hoff + rowoff + n, hn, b16);
        if (p.dup) stg1(Ar.outbase, p.h2off + rowoff + n, hn, b16);
      }
    }
}

extern "C" void kernel_launch(void* const* d_in, const int* in_sizes, int n_in,
                              void* d_out, int out_size, void* d_ws, size_t ws_size,
                              hipStream_t stream) {
  const void* kps   = d_in[0];
  const void* h0    = d_in[1];
  const void* h1    = d_in[2];
  const void* h2    = d_in[3];
  const void* c0    = d_in[4];
  const void* c1    = d_in[5];
  const void* c2    = d_in[6];
  const void* W_emb = d_in[7];
  const void* b_emb = d_in[8];
  const void* w_ih1 = d_in[9];
  const void* w_hh1 = d_in[10];
  const void* b_ih1 = d_in[11];
  const void* b_hh1 = d_in[12];
  const void* w_ih2 = d_in[13];
  const void* w_hh2 = d_in[14];
  const void* b_ih2 = d_in[15];
  const void* b_hh2 = d_in[16];
  const void* w_ih3 = d_in[17];
  const void* w_hh3 = d_in[18];
  const void* b_ih3 = d_in[19];
  const void* b_hh3 = d_in[20];

  const size_t S = (size_t)B_DIM * HID;

  const size_t E_SMALL = (size_t)4 * HID * KPSZ;     // 1,048,576
  const size_t E_BIG   = (size_t)4 * HID * HID;      // 4,194,304
  const size_t TOT_ELEMS = 2 * E_SMALL + 8 * E_BIG;  // 35,651,584
  const size_t NEED = TOT_ELEMS * 2;                 // 71,303,168 B

  if (ws_size >= NEED) {
    bf16* wsb      = (bf16*)d_ws;
    bf16* in_frame = wsb;
    bf16* W1x      = wsb + E_SMALL;
    bf16* W1h      = W1x + E_SMALL;
    bf16* W2x      = W1h + E_BIG;
    bf16* W2h      = W2x + E_BIG;
    bf16* W3x      = W2h + E_BIG;
    bf16* W3h      = W3x + E_BIG;
    bf16* H0       = W3h + E_BIG;
    bf16* H1       = H0 + E_BIG;
    bf16* H2       = H1 + E_BIG;

    PrepArgs P;
    const void* srcs[NSEG] = { w_ih1, w_hh1, w_ih2, w_hh2, w_ih3, w_hh3, h0, h1, h2 };
    bf16*       dsts[NSEG] = { W1x,   W1h,   W2x,   W2h,   W3x,   W3h,  H0, H1, H2 };
    unsigned    cnts[NSEG] = { (unsigned)(E_SMALL / 8), (unsigned)(E_BIG / 8),
                               (unsigned)(E_BIG / 8),   (unsigned)(E_BIG / 8),
                               (unsigned)(E_BIG / 8),   (unsigned)(E_BIG / 8),
                               (unsigned)(E_BIG / 8),   (unsigned)(E_BIG / 8),
                               (unsigned)(E_BIG / 8) };
    unsigned acc = 0;
    for (int i = 0; i < NSEG; ++i) {
      P.src[i] = srcs[i];
      P.dst[i] = dsts[i];
      P.pre[i] = acc;
      acc += cnts[i];
    }
    P.pre[NSEG] = acc;
    P.kps = kps; P.W_emb = W_emb; P.b_emb = b_emb; P.in_frame = in_frame;
    P.nconv = 2048;

    prep_kernel<<<dim3(256 + 2048), 256, 0, stream>>>(P);

    NArgs N;
    N.outbase = d_out;
    N.kps = kps;
    N.c[0] = { in_frame, W1x, H0, W1h, b_ih1, b_hh1, c0, 1 * S, 0, 4 * S, KPSZ, 0 };
    N.c[1] = { H0,       W2x, H1, W2h, b_ih2, b_hh2, c1, 2 * S, 0, 5 * S, HID,  0 };
    N.c[2] = { H1,       W3x, H2, W3h, b_ih3, b_hh3, c2, 0,     3 * S, 6 * S, HID, 1 };

    lstm_fast_kernel<<<dim3(HID / 32, B_DIM / 128, 3), 256, 0, stream>>>(N);
    return;
  }

  // -------- fallback: previous verified path --------
  void* in_frame = d_ws;
  emb_kernel<<<dim3(KPSZ / BNH, B_DIM / BM), 256, 0, stream>>>(kps, W_emb, b_emb, in_frame);

  Args3 A;
  A.outbase = d_out;
  A.kps = kps;
  A.c[0] = { in_frame, w_ih1, h0, w_hh1, b_ih1, b_hh1, c0,
             1 * S, 0, 4 * S, KPSZ, 0 };
  A.c[1] = { h0, w_ih2, h1, w_hh2, b_ih2, b_hh2, c1,
             2 * S, 0, 5 * S, HID, 0 };
  A.c[2] = { h1, w_ih3, h2, w_hh3, b_ih3, b_hh3, c2,
             0 * S, 3 * S, 6 * S, HID, 1 };

  lstm_cells_kernel<<<dim3(HID / BNH, B_DIM / BM, 3), 256, 0, stream>>>(A);
}